// Round 2
// baseline (3122.739 us; speedup 1.0000x reference)
//
#include <hip/hip_runtime.h>
#include <hip/hip_bf16.h>

#define NN 100000
#define NE 1600000
#define D  128

typedef unsigned short u16;
typedef unsigned int   u32;

__device__ __forceinline__ float b2f(u16 u){
  union { u32 i; float f; } v; v.i = ((u32)u) << 16; return v.f;
}
__device__ __forceinline__ u16 f2b(float f){
  union { float f; u32 i; } v; v.f = f;
  u32 r = v.i + 0x7fffu + ((v.i >> 16) & 1u);   // round-to-nearest-even
  return (u16)(r >> 16);
}

__global__ void k_deg_init(float* deg){
  int i = blockIdx.x * 256 + threadIdx.x;
  if (i < NN) deg[i] = 1.0f;                    // self-loop contributes 1
}
__global__ void k_deg_edges(const int* __restrict__ dst, float* __restrict__ deg){
  int e = blockIdx.x * 256 + threadIdx.x;
  if (e < NE) atomicAdd(&deg[dst[e]], 1.0f);
}
__global__ void k_dinv(float* deg){
  int i = blockIdx.x * 256 + threadIdx.x;
  if (i < NN) deg[i] = rsqrtf(deg[i]);          // deg >= 1 always
}

// out[n][128] = X @ W^T.  X = up to 3 chunks of [NN][128] (concat along K),
// each chunk f32 or bf16 per x_bf16 flag. W is f32 [128][kch*128] row-major.
// mode A (dinv != nullptr): g_out = h*dinv[row], acc_out = h*dinv^2 (f32)
// mode B: out = optional_relu(h + bias), written bf16 or f32 per out_bf16.
__global__ __launch_bounds__(256) void k_gemm(
    const void* xp0, const void* xp1, const void* xp2, int kch, int x_bf16,
    const float* __restrict__ W,
    const float* __restrict__ dinv,
    float* __restrict__ g_out, float* __restrict__ acc_out,
    const float* __restrict__ bias, int relu, int out_bf16,
    void* __restrict__ outp)
{
  __shared__ float XsT[128][32];   // [k][row] 16KB
  __shared__ float Wt[128][128];   // [k][out] 64KB
  const int tid = threadIdx.x;
  const int rowbase = blockIdx.x * 32;       // NN = 32 * 3125 exactly
  const int cg = tid & 31, rg = tid >> 5;
  const int c0 = cg * 4, r0 = rg * 4;
  const int wstride = kch * D;
  float acc[4][4] = {{0.f}};

  for (int c = 0; c < kch; ++c){
    const void* xc = (c == 0) ? xp0 : ((c == 1) ? xp1 : xp2);
    if (c) __syncthreads();
    // Wt[k][o] = W[o][c*128 + k]   (coalesced global reads, row o, 4 k's per thread)
    for (int i = tid; i < 4096; i += 256){
      int o = i >> 5, kb = (i & 31) * 4;
      float4 v = *(const float4*)(W + o * wstride + c * D + kb);
      Wt[kb + 0][o] = v.x; Wt[kb + 1][o] = v.y;
      Wt[kb + 2][o] = v.z; Wt[kb + 3][o] = v.w;
    }
    // XsT[k][r] = x[rowbase+r][k]
    if (x_bf16){
      const u16* xb = (const u16*)xc;
      for (int i = tid; i < 512; i += 256){
        int r = i >> 4, kb = (i & 15) * 8;
        uint4 v = *(const uint4*)(xb + (rowbase + r) * D + kb);
        const u16* pv = (const u16*)&v;
        #pragma unroll
        for (int j = 0; j < 8; ++j) XsT[kb + j][r] = b2f(pv[j]);
      }
    } else {
      const float* xf = (const float*)xc;
      for (int i = tid; i < 1024; i += 256){
        int r = i >> 5, kb = (i & 31) * 4;
        float4 v = *(const float4*)(xf + (rowbase + r) * D + kb);
        XsT[kb + 0][r] = v.x; XsT[kb + 1][r] = v.y;
        XsT[kb + 2][r] = v.z; XsT[kb + 3][r] = v.w;
      }
    }
    __syncthreads();
    #pragma unroll 16
    for (int k = 0; k < 128; ++k){
      float4 xv = *(const float4*)&XsT[k][r0];   // broadcast within lane-group
      float4 wv = *(const float4*)&Wt[k][c0];    // conflict-free (contiguous 512B)
      float xa[4] = {xv.x, xv.y, xv.z, xv.w};
      float wa[4] = {wv.x, wv.y, wv.z, wv.w};
      #pragma unroll
      for (int i2 = 0; i2 < 4; ++i2)
        #pragma unroll
        for (int j = 0; j < 4; ++j) acc[i2][j] += xa[i2] * wa[j];
    }
  }

  if (dinv){
    #pragma unroll
    for (int i = 0; i < 4; ++i){
      int row = rowbase + r0 + i;
      float di = dinv[row];
      float4 gv, av;
      gv.x = acc[i][0] * di; gv.y = acc[i][1] * di;
      gv.z = acc[i][2] * di; gv.w = acc[i][3] * di;
      av.x = gv.x * di; av.y = gv.y * di; av.z = gv.z * di; av.w = gv.w * di;
      *(float4*)(g_out   + row * D + c0) = gv;
      *(float4*)(acc_out + row * D + c0) = av;
    }
  } else {
    float b[4];
    #pragma unroll
    for (int j = 0; j < 4; ++j) b[j] = bias ? bias[c0 + j] : 0.f;
    #pragma unroll
    for (int i = 0; i < 4; ++i){
      int row = rowbase + r0 + i;
      float o0 = acc[i][0] + b[0], o1 = acc[i][1] + b[1];
      float o2 = acc[i][2] + b[2], o3 = acc[i][3] + b[3];
      if (relu){
        o0 = fmaxf(o0, 0.f); o1 = fmaxf(o1, 0.f);
        o2 = fmaxf(o2, 0.f); o3 = fmaxf(o3, 0.f);
      }
      if (out_bf16){
        ushort4 ov; ov.x = f2b(o0); ov.y = f2b(o1); ov.z = f2b(o2); ov.w = f2b(o3);
        *(ushort4*)((u16*)outp + row * D + c0) = ov;
      } else {
        float4 ov; ov.x = o0; ov.y = o1; ov.z = o2; ov.w = o3;
        *(float4*)((float*)outp + row * D + c0) = ov;
      }
    }
  }
}

// one thread per (edge, feature): acc[dst][f] += g[src][f] * dinv[dst]
__global__ __launch_bounds__(256) void k_scatter(
    const int* __restrict__ src, const int* __restrict__ dst,
    const float* __restrict__ g, const float* __restrict__ dinv,
    float* __restrict__ acc)
{
  u32 idx = blockIdx.x * 256u + threadIdx.x;
  u32 e = idx >> 7;
  int f = idx & 127;
  int s = src[e], d = dst[e];
  atomicAdd(acc + d * D + f, g[s * D + f] * dinv[d]);
}

// xs = bf16(relu(acc + bias)), one thread per 4 elements
__global__ void k_bias_relu(const float* __restrict__ acc,
                            const float* __restrict__ bias,
                            u16* __restrict__ out)
{
  int i = blockIdx.x * 256 + threadIdx.x;
  int base = i * 4;
  if (base >= NN * D) return;
  float4 v = *(const float4*)(acc + base);
  int f = base & (D - 1);
  float o0 = fmaxf(v.x + bias[f + 0], 0.f);
  float o1 = fmaxf(v.y + bias[f + 1], 0.f);
  float o2 = fmaxf(v.z + bias[f + 2], 0.f);
  float o3 = fmaxf(v.w + bias[f + 3], 0.f);
  ushort4 ov; ov.x = f2b(o0); ov.y = f2b(o1); ov.z = f2b(o2); ov.w = f2b(o3);
  *(ushort4*)(out + base) = ov;
}

extern "C" void kernel_launch(void* const* d_in, const int* in_sizes, int n_in,
                              void* d_out, int out_size, void* d_ws, size_t ws_size,
                              hipStream_t stream)
{
  const float* x   = (const float*)d_in[0];
  const int*   ei  = (const int*)d_in[1];
  const float* W0  = (const float*)d_in[2];
  const float* b0  = (const float*)d_in[3];
  const float* W1  = (const float*)d_in[4];
  const float* b1  = (const float*)d_in[5];
  const float* W2  = (const float*)d_in[6];
  const float* b2  = (const float*)d_in[7];
  const float* Wp0 = (const float*)d_in[8];
  const float* bp0 = (const float*)d_in[9];
  const float* Wp1 = (const float*)d_in[10];
  const float* bp1 = (const float*)d_in[11];
  const int* src = ei;
  const int* dst = ei + NE;

  char* ws = (char*)d_ws;
  // layout: dinv 512KB | g f32 51.2MB | acc f32 51.2MB | xs0..2 bf16 25.6MB each
  float* dinv = (float*)ws;
  float* g    = (float*)(ws + (512u << 10));
  float* acc  = (float*)(ws + (512u << 10) + 51200000u);
  u16* xs0 = (u16*)(ws + (512u << 10) + 2u * 51200000u);
  u16* xs1 = xs0 + NN * D;
  u16* xs2 = xs1 + NN * D;
  u16* z1  = (u16*)g;                 // g is dead by the time z1 is produced
  float* out = (float*)d_out;

  k_deg_init <<<(NN + 255) / 256, 256, 0, stream>>>(dinv);
  k_deg_edges<<<(NE + 255) / 256, 256, 0, stream>>>(dst, dinv);
  k_dinv     <<<(NN + 255) / 256, 256, 0, stream>>>(dinv);

  const float* Ws[3] = {W0, W1, W2};
  const float* bs[3] = {b0, b1, b2};
  u16* xsl[3] = {xs0, xs1, xs2};
  const void* xin = x;
  int xin_bf16 = 0;
  for (int l = 0; l < 3; ++l){
    k_gemm<<<NN / 32, 256, 0, stream>>>(xin, nullptr, nullptr, 1, xin_bf16, Ws[l],
                                        dinv, g, acc, nullptr, 0, 0, nullptr);
    k_scatter<<<NE / 2, 256, 0, stream>>>(src, dst, g, dinv, acc);
    k_bias_relu<<<NN * D / 1024, 256, 0, stream>>>(acc, bs[l], xsl[l]);
    xin = xsl[l]; xin_bf16 = 1;
  }
  // projection head: z1 = relu(hcat @ Wp0^T + bp0)   (bf16 out)
  k_gemm<<<NN / 32, 256, 0, stream>>>(xs0, xs1, xs2, 3, 1, Wp0,
                                      nullptr, nullptr, nullptr, bp0, 1, 1, z1);
  // out = z1 @ Wp1^T + bp1   (f32 out)
  k_gemm<<<NN / 32, 256, 0, stream>>>(z1, nullptr, nullptr, 1, 1, Wp1,
                                      nullptr, nullptr, nullptr, bp1, 0, 0, out);
}

// Round 4
// 1525.992 us; speedup vs baseline: 2.0464x; 2.0464x over previous
//
#include <hip/hip_runtime.h>
#include <hip/hip_bf16.h>

#define NN 100000
#define NE 1600000
#define D  128

typedef unsigned short u16;
typedef unsigned int   u32;

__device__ __forceinline__ float b2f(u16 u){
  union { u32 i; float f; } v; v.i = ((u32)u) << 16; return v.f;
}
__device__ __forceinline__ u16 f2b(float f){
  union { float f; u32 i; } v; v.f = f;
  u32 r = v.i + 0x7fffu + ((v.i >> 16) & 1u);   // round-to-nearest-even
  return (u16)(r >> 16);
}

// ---------------- CSR build ----------------
__global__ void k_count(const int* __restrict__ dst, int* __restrict__ cnt){
  int e = blockIdx.x * 256 + threadIdx.x;
  if (e < NE) atomicAdd(&cnt[dst[e]], 1);
}

// block-local exclusive scan of 256 counts -> row_ptr, block sums -> partials
__global__ __launch_bounds__(256) void k_scan1(const int* __restrict__ cnt,
                                               int* __restrict__ rp,
                                               int* __restrict__ partials){
  int i = blockIdx.x * 256 + threadIdx.x;
  int v = (i < NN) ? cnt[i] : 0;
  int lane = threadIdx.x & 63, w = threadIdx.x >> 6;
  int s = v;
  #pragma unroll
  for (int off = 1; off < 64; off <<= 1){
    int t = __shfl_up(s, off, 64);
    if (lane >= off) s += t;
  }
  __shared__ int wsum[4];
  if (lane == 63) wsum[w] = s;
  __syncthreads();
  int add = 0;
  #pragma unroll
  for (int k = 0; k < 4; ++k) if (k < w) add += wsum[k];
  s += add;
  if (i < NN) rp[i] = s - v;            // exclusive within block
  if (threadIdx.x == 255) partials[blockIdx.x] = s;
}

// single-block exclusive scan of the block sums (nb <= 512)
__global__ __launch_bounds__(512) void k_scan2(int* __restrict__ partials, int nb){
  int i = threadIdx.x;
  int v = (i < nb) ? partials[i] : 0;
  int lane = i & 63, w = i >> 6;
  int s = v;
  #pragma unroll
  for (int off = 1; off < 64; off <<= 1){
    int t = __shfl_up(s, off, 64);
    if (lane >= off) s += t;
  }
  __shared__ int wsum[8];
  if (lane == 63) wsum[w] = s;
  __syncthreads();
  int add = 0;
  #pragma unroll
  for (int k = 0; k < 8; ++k) if (k < w) add += wsum[k];
  s += add;
  if (i < nb) partials[i] = s - v;      // exclusive
}

// finalize row_ptr, init cursor, compute dinv = rsqrt(1 + indeg)
__global__ void k_scan3(int* __restrict__ rp, const int* __restrict__ partials,
                        const int* __restrict__ cnt,
                        int* __restrict__ cursor, float* __restrict__ dinv){
  int i = blockIdx.x * 256 + threadIdx.x;
  if (i < NN){
    int r = rp[i] + partials[blockIdx.x];
    rp[i] = r;
    cursor[i] = r;
    dinv[i] = rsqrtf(1.0f + (float)cnt[i]);
  }
  if (i == 0) rp[NN] = NE;
}

__global__ void k_fill(const int* __restrict__ src, const int* __restrict__ dst,
                       int* __restrict__ cursor, int* __restrict__ sorted){
  int e = blockIdx.x * 256 + threadIdx.x;
  if (e < NE){
    int pos = atomicAdd(&cursor[dst[e]], 1);
    sorted[pos] = src[e];
  }
}

// ---------------- GEMM ----------------
// out[n][128] = X @ W^T.  X = up to 3 chunks of [NN][128] (concat along K),
// each chunk f32 or bf16 per x_bf16 flag. W is f32 [128][kch*128] row-major.
// mode A (dinv != nullptr): g_out = h*dinv[row] (f32)
// mode B: out = optional_relu(h + bias), written bf16 or f32 per out_bf16.
__global__ __launch_bounds__(256) void k_gemm(
    const void* xp0, const void* xp1, const void* xp2, int kch, int x_bf16,
    const float* __restrict__ W,
    const float* __restrict__ dinv,
    float* __restrict__ g_out,
    const float* __restrict__ bias, int relu, int out_bf16,
    void* __restrict__ outp)
{
  __shared__ float XsT[128][32];   // [k][row] 16KB
  __shared__ float Wt[128][128];   // [k][out] 64KB
  const int tid = threadIdx.x;
  const int rowbase = blockIdx.x * 32;       // NN = 32 * 3125 exactly
  const int cg = tid & 31, rg = tid >> 5;
  const int c0 = cg * 4, r0 = rg * 4;
  const int wstride = kch * D;
  float acc[4][4] = {{0.f}};

  for (int c = 0; c < kch; ++c){
    const void* xc = (c == 0) ? xp0 : ((c == 1) ? xp1 : xp2);
    if (c) __syncthreads();
    for (int i = tid; i < 4096; i += 256){
      int o = i >> 5, kb = (i & 31) * 4;
      float4 v = *(const float4*)(W + o * wstride + c * D + kb);
      Wt[kb + 0][o] = v.x; Wt[kb + 1][o] = v.y;
      Wt[kb + 2][o] = v.z; Wt[kb + 3][o] = v.w;
    }
    if (x_bf16){
      const u16* xb = (const u16*)xc;
      for (int i = tid; i < 512; i += 256){
        int r = i >> 4, kb = (i & 15) * 8;
        uint4 v = *(const uint4*)(xb + (rowbase + r) * D + kb);
        const u16* pv = (const u16*)&v;
        #pragma unroll
        for (int j = 0; j < 8; ++j) XsT[kb + j][r] = b2f(pv[j]);
      }
    } else {
      const float* xf = (const float*)xc;
      for (int i = tid; i < 1024; i += 256){
        int r = i >> 5, kb = (i & 31) * 4;
        float4 v = *(const float4*)(xf + (rowbase + r) * D + kb);
        XsT[kb + 0][r] = v.x; XsT[kb + 1][r] = v.y;
        XsT[kb + 2][r] = v.z; XsT[kb + 3][r] = v.w;
      }
    }
    __syncthreads();
    #pragma unroll 16
    for (int k = 0; k < 128; ++k){
      float4 xv = *(const float4*)&XsT[k][r0];
      float4 wv = *(const float4*)&Wt[k][c0];
      float xa[4] = {xv.x, xv.y, xv.z, xv.w};
      float wa[4] = {wv.x, wv.y, wv.z, wv.w};
      #pragma unroll
      for (int i2 = 0; i2 < 4; ++i2)
        #pragma unroll
        for (int j = 0; j < 4; ++j) acc[i2][j] += xa[i2] * wa[j];
    }
  }

  if (dinv){
    #pragma unroll
    for (int i = 0; i < 4; ++i){
      int row = rowbase + r0 + i;
      float di = dinv[row];
      float4 gv;
      gv.x = acc[i][0] * di; gv.y = acc[i][1] * di;
      gv.z = acc[i][2] * di; gv.w = acc[i][3] * di;
      *(float4*)(g_out + row * D + c0) = gv;
    }
  } else {
    float b[4];
    #pragma unroll
    for (int j = 0; j < 4; ++j) b[j] = bias ? bias[c0 + j] : 0.f;
    #pragma unroll
    for (int i = 0; i < 4; ++i){
      int row = rowbase + r0 + i;
      float o0 = acc[i][0] + b[0], o1 = acc[i][1] + b[1];
      float o2 = acc[i][2] + b[2], o3 = acc[i][3] + b[3];
      if (relu){
        o0 = fmaxf(o0, 0.f); o1 = fmaxf(o1, 0.f);
        o2 = fmaxf(o2, 0.f); o3 = fmaxf(o3, 0.f);
      }
      if (out_bf16){
        ushort4 ov; ov.x = f2b(o0); ov.y = f2b(o1); ov.z = f2b(o2); ov.w = f2b(o3);
        *(ushort4*)((u16*)outp + row * D + c0) = ov;
      } else {
        float4 ov; ov.x = o0; ov.y = o1; ov.z = o2; ov.w = o3;
        *(float4*)((float*)outp + row * D + c0) = ov;
      }
    }
  }
}

// ---------------- CSR aggregation, fused epilogue ----------------
// wave per node, lane l holds features {2l, 2l+1}
// xs[n][f] = bf16(relu(dinv[n]*(g[n][f] + sum_e g[src_e][f]) + bias[f]))
__global__ __launch_bounds__(256) void k_aggr(
    const int* __restrict__ rp, const int* __restrict__ sorted,
    const float* __restrict__ g, const float* __restrict__ dinv,
    const float* __restrict__ bias, u16* __restrict__ xs)
{
  int node = blockIdx.x * 4 + (threadIdx.x >> 6);
  int l = threadIdx.x & 63;
  const float2* g2 = (const float2*)g;
  int e0 = rp[node], e1 = rp[node + 1];
  float2 acc = g2[node * 64 + l];          // self-loop term
  int e = e0;
  for (; e + 1 < e1; e += 2){
    int s0 = sorted[e], s1 = sorted[e + 1];
    float2 a = g2[s0 * 64 + l], b = g2[s1 * 64 + l];
    acc.x += a.x + b.x; acc.y += a.y + b.y;
  }
  if (e < e1){
    int s0 = sorted[e];
    float2 a = g2[s0 * 64 + l];
    acc.x += a.x; acc.y += a.y;
  }
  float dn = dinv[node];
  float o0 = fmaxf(fmaf(acc.x, dn, bias[2 * l]),     0.f);
  float o1 = fmaxf(fmaf(acc.y, dn, bias[2 * l + 1]), 0.f);
  u32 pk = ((u32)f2b(o1) << 16) | (u32)f2b(o0);
  ((u32*)xs)[node * 64 + l] = pk;
}

extern "C" void kernel_launch(void* const* d_in, const int* in_sizes, int n_in,
                              void* d_out, int out_size, void* d_ws, size_t ws_size,
                              hipStream_t stream)
{
  const float* x   = (const float*)d_in[0];
  const int*   ei  = (const int*)d_in[1];
  const float* W0  = (const float*)d_in[2];
  const float* b0  = (const float*)d_in[3];
  const float* W1  = (const float*)d_in[4];
  const float* b1  = (const float*)d_in[5];
  const float* W2  = (const float*)d_in[6];
  const float* b2  = (const float*)d_in[7];
  const float* Wp0 = (const float*)d_in[8];
  const float* bp0 = (const float*)d_in[9];
  const float* Wp1 = (const float*)d_in[10];
  const float* bp1 = (const float*)d_in[11];
  const int* src = ei;
  const int* dst = ei + NE;

  char* ws = (char*)d_ws;
  float* dinv    = (float*)(ws);                    // 400KB
  int*   cnt     = (int*)  (ws + (512u << 10));     // 400KB
  int*   rp      = (int*)  (ws + (1024u << 10));    // 400KB+4
  int*   cursor  = (int*)  (ws + (1536u << 10));    // 400KB
  int*   partials= (int*)  (ws + (2048u << 10));    // 2KB
  int*   sorted  = (int*)  (ws + (2560u << 10));    // 6.4MB
  float* g       = (float*)(ws + (16384u << 10));   // 51.2MB
  u16*   xs0     = (u16*)  (ws + (81920u << 10));   // 25.6MB
  u16*   xs1     = xs0 + NN * D;
  u16*   xs2     = xs1 + NN * D;
  u16*   z1      = (u16*)g;                         // g dead when z1 produced
  float* out     = (float*)d_out;

  const int NB = (NN + 255) / 256;   // 391

  hipMemsetAsync(cnt, 0, NN * sizeof(int), stream);
  k_count<<<NE / 256, 256, 0, stream>>>(dst, cnt);
  k_scan1<<<NB, 256, 0, stream>>>(cnt, rp, partials);
  k_scan2<<<1, 512, 0, stream>>>(partials, NB);
  k_scan3<<<NB, 256, 0, stream>>>(rp, partials, cnt, cursor, dinv);
  k_fill <<<NE / 256, 256, 0, stream>>>(src, dst, cursor, sorted);

  const float* Ws[3] = {W0, W1, W2};
  const float* bs[3] = {b0, b1, b2};
  u16* xsl[3] = {xs0, xs1, xs2};
  const void* xin = x;
  int xin_bf16 = 0;
  for (int l = 0; l < 3; ++l){
    k_gemm<<<NN / 32, 256, 0, stream>>>(xin, nullptr, nullptr, 1, xin_bf16, Ws[l],
                                        dinv, g, nullptr, 0, 0, nullptr);
    k_aggr<<<NN / 4, 256, 0, stream>>>(rp, sorted, g, dinv, bs[l], xsl[l]);
    xin = xsl[l]; xin_bf16 = 1;
  }
  // projection head: z1 = relu(hcat @ Wp0^T + bp0)   (bf16 out)
  k_gemm<<<NN / 32, 256, 0, stream>>>(xs0, xs1, xs2, 3, 1, Wp0,
                                      nullptr, nullptr, bp0, 1, 1, z1);
  // out = z1 @ Wp1^T + bp1   (f32 out)
  k_gemm<<<NN / 32, 256, 0, stream>>>(z1, nullptr, nullptr, 1, 1, Wp1,
                                      nullptr, nullptr, bp1, 0, 0, out);
}

// Round 5
// 1026.867 us; speedup vs baseline: 3.0410x; 1.4861x over previous
//
#include <hip/hip_runtime.h>
#include <hip/hip_bf16.h>

#define NN 100000
#define NE 1600000
#define D  128

typedef unsigned short u16;
typedef unsigned int   u32;

__device__ __forceinline__ float b2f(u16 u){
  union { u32 i; float f; } v; v.i = ((u32)u) << 16; return v.f;
}
__device__ __forceinline__ u16 f2b(float f){
  union { float f; u32 i; } v; v.f = f;
  u32 r = v.i + 0x7fffu + ((v.i >> 16) & 1u);   // round-to-nearest-even
  return (u16)(r >> 16);
}

// ---------------- CSR build ----------------
__global__ void k_count(const int* __restrict__ dst, int* __restrict__ cnt){
  int e = blockIdx.x * 256 + threadIdx.x;
  if (e < NE) atomicAdd(&cnt[dst[e]], 1);
}

__global__ __launch_bounds__(256) void k_scan1(const int* __restrict__ cnt,
                                               int* __restrict__ rp,
                                               int* __restrict__ partials){
  int i = blockIdx.x * 256 + threadIdx.x;
  int v = (i < NN) ? cnt[i] : 0;
  int lane = threadIdx.x & 63, w = threadIdx.x >> 6;
  int s = v;
  #pragma unroll
  for (int off = 1; off < 64; off <<= 1){
    int t = __shfl_up(s, off, 64);
    if (lane >= off) s += t;
  }
  __shared__ int wsum[4];
  if (lane == 63) wsum[w] = s;
  __syncthreads();
  int add = 0;
  #pragma unroll
  for (int k = 0; k < 4; ++k) if (k < w) add += wsum[k];
  s += add;
  if (i < NN) rp[i] = s - v;            // exclusive within block
  if (threadIdx.x == 255) partials[blockIdx.x] = s;
}

__global__ __launch_bounds__(512) void k_scan2(int* __restrict__ partials, int nb){
  int i = threadIdx.x;
  int v = (i < nb) ? partials[i] : 0;
  int lane = i & 63, w = i >> 6;
  int s = v;
  #pragma unroll
  for (int off = 1; off < 64; off <<= 1){
    int t = __shfl_up(s, off, 64);
    if (lane >= off) s += t;
  }
  __shared__ int wsum[8];
  if (lane == 63) wsum[w] = s;
  __syncthreads();
  int add = 0;
  #pragma unroll
  for (int k = 0; k < 8; ++k) if (k < w) add += wsum[k];
  s += add;
  if (i < nb) partials[i] = s - v;      // exclusive
}

__global__ void k_scan3(int* __restrict__ rp, const int* __restrict__ partials,
                        const int* __restrict__ cnt,
                        int* __restrict__ cursor, float* __restrict__ dinv){
  int i = blockIdx.x * 256 + threadIdx.x;
  if (i < NN){
    int r = rp[i] + partials[blockIdx.x];
    rp[i] = r;
    cursor[i] = r;
    dinv[i] = rsqrtf(1.0f + (float)cnt[i]);
  }
  if (i == 0) rp[NN] = NE;
}

__global__ void k_fill(const int* __restrict__ src, const int* __restrict__ dst,
                       int* __restrict__ cursor, int* __restrict__ sorted){
  int e = blockIdx.x * 256 + threadIdx.x;
  if (e < NE){
    int pos = atomicAdd(&cursor[dst[e]], 1);
    sorted[pos] = src[e];
  }
}

// ---------------- GEMM ----------------
// out[n][128] = X @ W^T.  X = up to 3 chunks of [NN][128] (concat along K),
// each chunk f32 or bf16 per x_bf16 flag. W is f32 [128][kch*128] row-major.
// mode A (dinv != nullptr): g_out = h*dinv[row] (f32)
// mode B: out = optional_relu(h + bias), written bf16 or f32 per out_bf16.
//
// LDS staging: lane-varying index is the COLUMN of the tile (bank = col%32,
// consecutive cols across lanes -> 2 lanes/bank = conflict-free per m136).
__global__ __launch_bounds__(256) void k_gemm(
    const void* xp0, const void* xp1, const void* xp2, int kch, int x_bf16,
    const float* __restrict__ W,
    const float* __restrict__ dinv,
    float* __restrict__ g_out,
    const float* __restrict__ bias, int relu, int out_bf16,
    void* __restrict__ outp)
{
  __shared__ float XsT[128][32];   // [k][row] 16KB
  __shared__ float Wt[128][128];   // [k][out] 64KB
  const int tid = threadIdx.x;
  const int rowbase = blockIdx.x * 32;       // NN = 32 * 3125 exactly
  const int cg = tid & 31, rg = tid >> 5;
  const int c0 = cg * 4, r0 = rg * 4;
  const int wstride = kch * D;
  float acc[4][4] = {{0.f}};

  for (int c = 0; c < kch; ++c){
    const void* xc = (c == 0) ? xp0 : ((c == 1) ? xp1 : xp2);
    if (c) __syncthreads();
    // Wt[kb+j][o] = W[o][c*128+kb+j]; o = lane-varying -> conflict-free writes
    for (int i = tid; i < 4096; i += 256){
      int o = i & 127, kb = (i >> 7) * 4;
      float4 v = *(const float4*)(W + o * wstride + c * D + kb);
      Wt[kb + 0][o] = v.x; Wt[kb + 1][o] = v.y;
      Wt[kb + 2][o] = v.z; Wt[kb + 3][o] = v.w;
    }
    // XsT[kb+j][r] = x[rowbase+r][kb+j]; r = lane-varying -> conflict-free writes
    if (x_bf16){
      const u16* xb = (const u16*)xc;
      for (int i = tid; i < 512; i += 256){
        int r = i & 31, kb = (i >> 5) * 8;
        uint4 v = *(const uint4*)(xb + (rowbase + r) * D + kb);
        const u16* pv = (const u16*)&v;
        #pragma unroll
        for (int j = 0; j < 8; ++j) XsT[kb + j][r] = b2f(pv[j]);
      }
    } else {
      const float* xf = (const float*)xc;
      for (int i = tid; i < 1024; i += 256){
        int r = i & 31, kb = (i >> 5) * 4;
        float4 v = *(const float4*)(xf + (rowbase + r) * D + kb);
        XsT[kb + 0][r] = v.x; XsT[kb + 1][r] = v.y;
        XsT[kb + 2][r] = v.z; XsT[kb + 3][r] = v.w;
      }
    }
    __syncthreads();
    #pragma unroll 16
    for (int k = 0; k < 128; ++k){
      float4 xv = *(const float4*)&XsT[k][r0];   // broadcast within lane-group
      float4 wv = *(const float4*)&Wt[k][c0];    // contiguous stride-1 b128
      float xa[4] = {xv.x, xv.y, xv.z, xv.w};
      float wa[4] = {wv.x, wv.y, wv.z, wv.w};
      #pragma unroll
      for (int i2 = 0; i2 < 4; ++i2)
        #pragma unroll
        for (int j = 0; j < 4; ++j) acc[i2][j] += xa[i2] * wa[j];
    }
  }

  if (dinv){
    #pragma unroll
    for (int i = 0; i < 4; ++i){
      int row = rowbase + r0 + i;
      float di = dinv[row];
      float4 gv;
      gv.x = acc[i][0] * di; gv.y = acc[i][1] * di;
      gv.z = acc[i][2] * di; gv.w = acc[i][3] * di;
      *(float4*)(g_out + row * D + c0) = gv;
    }
  } else {
    float b[4];
    #pragma unroll
    for (int j = 0; j < 4; ++j) b[j] = bias ? bias[c0 + j] : 0.f;
    #pragma unroll
    for (int i = 0; i < 4; ++i){
      int row = rowbase + r0 + i;
      float o0 = acc[i][0] + b[0], o1 = acc[i][1] + b[1];
      float o2 = acc[i][2] + b[2], o3 = acc[i][3] + b[3];
      if (relu){
        o0 = fmaxf(o0, 0.f); o1 = fmaxf(o1, 0.f);
        o2 = fmaxf(o2, 0.f); o3 = fmaxf(o3, 0.f);
      }
      if (out_bf16){
        ushort4 ov; ov.x = f2b(o0); ov.y = f2b(o1); ov.z = f2b(o2); ov.w = f2b(o3);
        *(ushort4*)((u16*)outp + row * D + c0) = ov;
      } else {
        float4 ov; ov.x = o0; ov.y = o1; ov.z = o2; ov.w = o3;
        *(float4*)((float*)outp + row * D + c0) = ov;
      }
    }
  }
}

// ---------------- CSR aggregation, fused epilogue ----------------
// wave per node, lane l holds features {2l, 2l+1}
// xs[n][f] = bf16(relu(dinv[n]*(g[n][f] + sum_e g[src_e][f]) + bias[f]))
__global__ __launch_bounds__(256) void k_aggr(
    const int* __restrict__ rp, const int* __restrict__ sorted,
    const float* __restrict__ g, const float* __restrict__ dinv,
    const float* __restrict__ bias, u16* __restrict__ xs)
{
  int node = blockIdx.x * 4 + (threadIdx.x >> 6);
  int l = threadIdx.x & 63;
  const float2* g2 = (const float2*)g;
  int e0 = rp[node], e1 = rp[node + 1];
  float2 acc = g2[node * 64 + l];          // self-loop term
  int e = e0;
  for (; e + 1 < e1; e += 2){
    int s0 = sorted[e], s1 = sorted[e + 1];
    float2 a = g2[s0 * 64 + l], b = g2[s1 * 64 + l];
    acc.x += a.x + b.x; acc.y += a.y + b.y;
  }
  if (e < e1){
    int s0 = sorted[e];
    float2 a = g2[s0 * 64 + l];
    acc.x += a.x; acc.y += a.y;
  }
  float dn = dinv[node];
  float o0 = fmaxf(fmaf(acc.x, dn, bias[2 * l]),     0.f);
  float o1 = fmaxf(fmaf(acc.y, dn, bias[2 * l + 1]), 0.f);
  u32 pk = ((u32)f2b(o1) << 16) | (u32)f2b(o0);
  ((u32*)xs)[node * 64 + l] = pk;
}

extern "C" void kernel_launch(void* const* d_in, const int* in_sizes, int n_in,
                              void* d_out, int out_size, void* d_ws, size_t ws_size,
                              hipStream_t stream)
{
  const float* x   = (const float*)d_in[0];
  const int*   ei  = (const int*)d_in[1];
  const float* W0  = (const float*)d_in[2];
  const float* b0  = (const float*)d_in[3];
  const float* W1  = (const float*)d_in[4];
  const float* b1  = (const float*)d_in[5];
  const float* W2  = (const float*)d_in[6];
  const float* b2  = (const float*)d_in[7];
  const float* Wp0 = (const float*)d_in[8];
  const float* bp0 = (const float*)d_in[9];
  const float* Wp1 = (const float*)d_in[10];
  const float* bp1 = (const float*)d_in[11];
  const int* src = ei;
  const int* dst = ei + NE;

  char* ws = (char*)d_ws;
  float* dinv    = (float*)(ws);                    // 400KB
  int*   cnt     = (int*)  (ws + (512u << 10));     // 400KB
  int*   rp      = (int*)  (ws + (1024u << 10));    // 400KB+4
  int*   cursor  = (int*)  (ws + (1536u << 10));    // 400KB
  int*   partials= (int*)  (ws + (2048u << 10));    // 2KB
  int*   sorted  = (int*)  (ws + (2560u << 10));    // 6.4MB
  float* g       = (float*)(ws + (16384u << 10));   // 51.2MB
  u16*   xs0     = (u16*)  (ws + (81920u << 10));   // 25.6MB
  u16*   xs1     = xs0 + NN * D;
  u16*   xs2     = xs1 + NN * D;
  u16*   z1      = (u16*)g;                         // g dead when z1 produced
  float* out     = (float*)d_out;

  const int NB = (NN + 255) / 256;   // 391

  hipMemsetAsync(cnt, 0, NN * sizeof(int), stream);
  k_count<<<NE / 256, 256, 0, stream>>>(dst, cnt);
  k_scan1<<<NB, 256, 0, stream>>>(cnt, rp, partials);
  k_scan2<<<1, 512, 0, stream>>>(partials, NB);
  k_scan3<<<NB, 256, 0, stream>>>(rp, partials, cnt, cursor, dinv);
  k_fill <<<NE / 256, 256, 0, stream>>>(src, dst, cursor, sorted);

  const float* Ws[3] = {W0, W1, W2};
  const float* bs[3] = {b0, b1, b2};
  u16* xsl[3] = {xs0, xs1, xs2};
  const void* xin = x;
  int xin_bf16 = 0;
  for (int l = 0; l < 3; ++l){
    k_gemm<<<NN / 32, 256, 0, stream>>>(xin, nullptr, nullptr, 1, xin_bf16, Ws[l],
                                        dinv, g, nullptr, 0, 0, nullptr);
    k_aggr<<<NN / 4, 256, 0, stream>>>(rp, sorted, g, dinv, bs[l], xsl[l]);
    xin = xsl[l]; xin_bf16 = 1;
  }
  // projection head: z1 = relu(hcat @ Wp0^T + bp0)   (bf16 out)
  k_gemm<<<NN / 32, 256, 0, stream>>>(xs0, xs1, xs2, 3, 1, Wp0,
                                      nullptr, nullptr, bp0, 1, 1, z1);
  // out = z1 @ Wp1^T + bp1   (f32 out)
  k_gemm<<<NN / 32, 256, 0, stream>>>(z1, nullptr, nullptr, 1, 1, Wp1,
                                      nullptr, nullptr, bp1, 0, 0, out);
}

// Round 6
// 766.948 us; speedup vs baseline: 4.0716x; 1.3389x over previous
//
#include <hip/hip_runtime.h>
#include <hip/hip_bf16.h>

#define NN 100000
#define NE 1600000
#define D  128

typedef unsigned short u16;
typedef unsigned int   u32;
typedef __attribute__((ext_vector_type(8))) short short8v;
typedef __attribute__((ext_vector_type(4))) float f32x4;

__device__ __forceinline__ float b2f(u16 u){
  union { u32 i; float f; } v; v.i = ((u32)u) << 16; return v.f;
}
__device__ __forceinline__ u16 f2b(float f){
  union { float f; u32 i; } v; v.f = f;
  u32 r = v.i + 0x7fffu + ((v.i >> 16) & 1u);   // round-to-nearest-even
  return (u16)(r >> 16);
}

// ---------------- split f32 -> bf16 hi + bf16 lo ----------------
__global__ void k_split(const float* __restrict__ s, u16* __restrict__ hi,
                        u16* __restrict__ lo, int n4){
  int i = blockIdx.x * 256 + threadIdx.x;
  if (i >= n4) return;
  float4 v = ((const float4*)s)[i];
  ushort4 h, l;
  h.x = f2b(v.x); l.x = f2b(v.x - b2f(h.x));
  h.y = f2b(v.y); l.y = f2b(v.y - b2f(h.y));
  h.z = f2b(v.z); l.z = f2b(v.z - b2f(h.z));
  h.w = f2b(v.w); l.w = f2b(v.w - b2f(h.w));
  ((ushort4*)hi)[i] = h; ((ushort4*)lo)[i] = l;
}

// ---------------- CSR build ----------------
__global__ void k_count(const int* __restrict__ dst, int* __restrict__ cnt){
  int e = blockIdx.x * 256 + threadIdx.x;
  if (e < NE) atomicAdd(&cnt[dst[e]], 1);
}

__global__ __launch_bounds__(256) void k_scan1(const int* __restrict__ cnt,
                                               int* __restrict__ rp,
                                               int* __restrict__ partials){
  int i = blockIdx.x * 256 + threadIdx.x;
  int v = (i < NN) ? cnt[i] : 0;
  int lane = threadIdx.x & 63, w = threadIdx.x >> 6;
  int s = v;
  #pragma unroll
  for (int off = 1; off < 64; off <<= 1){
    int t = __shfl_up(s, off, 64);
    if (lane >= off) s += t;
  }
  __shared__ int wsum[4];
  if (lane == 63) wsum[w] = s;
  __syncthreads();
  int add = 0;
  #pragma unroll
  for (int k = 0; k < 4; ++k) if (k < w) add += wsum[k];
  s += add;
  if (i < NN) rp[i] = s - v;
  if (threadIdx.x == 255) partials[blockIdx.x] = s;
}

__global__ __launch_bounds__(512) void k_scan2(int* __restrict__ partials, int nb){
  int i = threadIdx.x;
  int v = (i < nb) ? partials[i] : 0;
  int lane = i & 63, w = i >> 6;
  int s = v;
  #pragma unroll
  for (int off = 1; off < 64; off <<= 1){
    int t = __shfl_up(s, off, 64);
    if (lane >= off) s += t;
  }
  __shared__ int wsum[8];
  if (lane == 63) wsum[w] = s;
  __syncthreads();
  int add = 0;
  #pragma unroll
  for (int k = 0; k < 8; ++k) if (k < w) add += wsum[k];
  s += add;
  if (i < nb) partials[i] = s - v;
}

__global__ void k_scan3(int* __restrict__ rp, const int* __restrict__ partials,
                        const int* __restrict__ cnt,
                        int* __restrict__ cursor, float* __restrict__ dinv){
  int i = blockIdx.x * 256 + threadIdx.x;
  if (i < NN){
    int r = rp[i] + partials[blockIdx.x];
    rp[i] = r;
    cursor[i] = r;
    dinv[i] = rsqrtf(1.0f + (float)cnt[i]);
  }
  if (i == 0) rp[NN] = NE;
}

__global__ void k_fill(const int* __restrict__ src, const int* __restrict__ dst,
                       int* __restrict__ cursor, int* __restrict__ sorted){
  int e = blockIdx.x * 256 + threadIdx.x;
  if (e < NE){
    int pos = atomicAdd(&cursor[dst[e]], 1);
    sorted[pos] = src[e];
  }
}

// ---------------- MFMA GEMM ----------------
// out[n][128] = A @ W^T.  A = up to 3 bf16 chunks [NN][128] (concat on K);
// al0 (optional) = lo-part of chunk 0 (split-f32).  Wh/Wl bf16 [128][kch*128].
// mode A (dinv): g_out[row][col] = h*dinv[row] (f32)
// mode B: out = optional_relu(h + bias) -> bf16 or f32.
// Fragment maps (mfma_f32_16x16x32_bf16): A row=lane&15,k=(lane>>4)*8+j;
// B col=lane&15 (W row), same k; D col=lane&15,row=(lane>>4)*4+reg (verified).
__global__ __launch_bounds__(256) void k_mgemm(
    const u16* __restrict__ a0, const u16* __restrict__ a1, const u16* __restrict__ a2,
    const u16* __restrict__ al0, int kch,
    const u16* __restrict__ Wh, const u16* __restrict__ Wl,
    const float* __restrict__ dinv, float* __restrict__ g_out,
    const float* __restrict__ bias, int relu, int out_bf16,
    void* __restrict__ outp)
{
  __shared__ u16 WHs[16384];   // 32KB, XOR-swizzled rows
  __shared__ u16 WLs[16384];   // 32KB
  const int tid  = threadIdx.x;
  const int w    = tid >> 6, lane = tid & 63;
  const int c    = lane & 15, q = lane >> 4;
  const int rowbase = blockIdx.x * 64 + w * 16;
  const int wstride = kch * D;
  const int swz = (c & 7) << 4;

  int arow = rowbase + c;
  if (arow >= NN) arow = NN - 1;        // clamp; stores are predicated

  f32x4 acc[8];
  #pragma unroll
  for (int f = 0; f < 8; ++f) acc[f] = (f32x4){0.f, 0.f, 0.f, 0.f};

  for (int cc = 0; cc < kch; ++cc){
    if (cc) __syncthreads();
    // stage W chunk (hi & lo) into LDS, swizzled: byte = (o*256 + k*2) ^ ((o&7)<<4)
    for (int t = 0; t < 2; ++t){
      const u16* Wsrc = t ? Wl : Wh;
      char* Ldst = (char*)(t ? WLs : WHs);
      for (int idx = tid; idx < 2048; idx += 256){
        int o = idx >> 4, ks = (idx & 15) * 8;
        uint4 v = *(const uint4*)(Wsrc + o * wstride + cc * D + ks);
        *(uint4*)(Ldst + ((o * 256 + ks * 2) ^ ((o & 7) << 4))) = v;
      }
    }
    __syncthreads();

    const u16* ach = (cc == 0) ? a0 : ((cc == 1) ? a1 : a2);
    #pragma unroll
    for (int kk = 0; kk < 4; ++kk){
      const int koff = kk * 32 + q * 8;
      short8v ah = *(const short8v*)(ach + arow * D + koff);
      short8v alv;
      if (al0) alv = *(const short8v*)(al0 + arow * D + koff);
      #pragma unroll
      for (int f = 0; f < 8; ++f){
        const int lrow = f * 16 + c;
        const int lbyte = (lrow * 256 + kk * 64 + q * 16) ^ swz;
        short8v bh = *(const short8v*)((const char*)WHs + lbyte);
        short8v bl = *(const short8v*)((const char*)WLs + lbyte);
        acc[f] = __builtin_amdgcn_mfma_f32_16x16x32_bf16(ah, bh, acc[f], 0, 0, 0);
        acc[f] = __builtin_amdgcn_mfma_f32_16x16x32_bf16(ah, bl, acc[f], 0, 0, 0);
        if (al0)
          acc[f] = __builtin_amdgcn_mfma_f32_16x16x32_bf16(alv, bh, acc[f], 0, 0, 0);
      }
    }
  }

  if (dinv){
    #pragma unroll
    for (int i = 0; i < 4; ++i){
      int row = rowbase + q * 4 + i;
      if (row < NN){
        float di = dinv[row];
        #pragma unroll
        for (int f = 0; f < 8; ++f)
          g_out[row * D + f * 16 + c] = acc[f][i] * di;
      }
    }
  } else {
    float bv[8];
    #pragma unroll
    for (int f = 0; f < 8; ++f) bv[f] = bias[f * 16 + c];
    #pragma unroll
    for (int i = 0; i < 4; ++i){
      int row = rowbase + q * 4 + i;
      if (row < NN){
        #pragma unroll
        for (int f = 0; f < 8; ++f){
          float o = acc[f][i] + bv[f];
          if (relu) o = fmaxf(o, 0.f);
          if (out_bf16) ((u16*)outp)[row * D + f * 16 + c] = f2b(o);
          else          ((float*)outp)[row * D + f * 16 + c] = o;
        }
      }
    }
  }
}

// ---------------- CSR aggregation, fused epilogue ----------------
__global__ __launch_bounds__(256) void k_aggr(
    const int* __restrict__ rp, const int* __restrict__ sorted,
    const float* __restrict__ g, const float* __restrict__ dinv,
    const float* __restrict__ bias, u16* __restrict__ xs)
{
  int node = blockIdx.x * 4 + (threadIdx.x >> 6);
  int l = threadIdx.x & 63;
  const float2* g2 = (const float2*)g;
  int e0 = rp[node], e1 = rp[node + 1];
  float2 acc = g2[node * 64 + l];          // self-loop term
  int e = e0;
  for (; e + 1 < e1; e += 2){
    int s0 = sorted[e], s1 = sorted[e + 1];
    float2 a = g2[s0 * 64 + l], b = g2[s1 * 64 + l];
    acc.x += a.x + b.x; acc.y += a.y + b.y;
  }
  if (e < e1){
    int s0 = sorted[e];
    float2 a = g2[s0 * 64 + l];
    acc.x += a.x; acc.y += a.y;
  }
  float dn = dinv[node];
  float o0 = fmaxf(fmaf(acc.x, dn, bias[2 * l]),     0.f);
  float o1 = fmaxf(fmaf(acc.y, dn, bias[2 * l + 1]), 0.f);
  u32 pk = ((u32)f2b(o1) << 16) | (u32)f2b(o0);
  ((u32*)xs)[node * 64 + l] = pk;
}

extern "C" void kernel_launch(void* const* d_in, const int* in_sizes, int n_in,
                              void* d_out, int out_size, void* d_ws, size_t ws_size,
                              hipStream_t stream)
{
  const float* x   = (const float*)d_in[0];
  const int*   ei  = (const int*)d_in[1];
  const float* W0  = (const float*)d_in[2];
  const float* b0  = (const float*)d_in[3];
  const float* W1  = (const float*)d_in[4];
  const float* b1  = (const float*)d_in[5];
  const float* W2  = (const float*)d_in[6];
  const float* b2  = (const float*)d_in[7];
  const float* Wp0 = (const float*)d_in[8];
  const float* bp0 = (const float*)d_in[9];
  const float* Wp1 = (const float*)d_in[10];
  const float* bp1 = (const float*)d_in[11];
  const int* src = ei;
  const int* dst = ei + NE;

  char* ws = (char*)d_ws;
  float* dinv    = (float*)(ws);                    // 400KB
  int*   cnt     = (int*)  (ws + (512u << 10));
  int*   rp      = (int*)  (ws + (1024u << 10));
  int*   cursor  = (int*)  (ws + (1536u << 10));
  int*   partials= (int*)  (ws + (2048u << 10));
  int*   sorted  = (int*)  (ws + (2560u << 10));    // 6.4MB
  // weight splits at 9MB
  u16* W0h = (u16*)(ws + 9437184u);            u16* W0l = W0h + 16384;
  u16* W1h = W0l + 16384;                      u16* W1l = W1h + 16384;
  u16* W2h = W1l + 16384;                      u16* W2l = W2h + 16384;
  u16* Wp0h = W2l + 16384;                     u16* Wp0l = Wp0h + 49152;
  u16* Wp1h = Wp0l + 49152;                    u16* Wp1l = Wp1h + 16384;
  float* g   = (float*)(ws + (16384u << 10));       // 51.2MB
  u16*  xs0  = (u16*)  (ws + (81920u << 10));       // 25.6MB each
  u16*  xs1  = xs0 + NN * D;
  u16*  xs2  = xs1 + NN * D;
  u16*  z1   = (u16*)g;          // g dead when z1 produced
  u16*  xh   = xs2;              // x hi/lo alias xs2/xs1 (dead before overwrite)
  u16*  xl   = xs1;
  float* out = (float*)d_out;

  const int NB = (NN + 255) / 256;   // 391

  // input conversions
  k_split<<<12500, 256, 0, stream>>>(x, xh, xl, NN * D / 4);
  k_split<<<16, 256, 0, stream>>>(W0, W0h, W0l, 16384 / 4);
  k_split<<<16, 256, 0, stream>>>(W1, W1h, W1l, 16384 / 4);
  k_split<<<16, 256, 0, stream>>>(W2, W2h, W2l, 16384 / 4);
  k_split<<<48, 256, 0, stream>>>(Wp0, Wp0h, Wp0l, 49152 / 4);
  k_split<<<16, 256, 0, stream>>>(Wp1, Wp1h, Wp1l, 16384 / 4);

  // CSR build
  hipMemsetAsync(cnt, 0, NN * sizeof(int), stream);
  k_count<<<NE / 256, 256, 0, stream>>>(dst, cnt);
  k_scan1<<<NB, 256, 0, stream>>>(cnt, rp, partials);
  k_scan2<<<1, 512, 0, stream>>>(partials, NB);
  k_scan3<<<NB, 256, 0, stream>>>(rp, partials, cnt, cursor, dinv);
  k_fill <<<NE / 256, 256, 0, stream>>>(src, dst, cursor, sorted);

  const int GB = (NN + 63) / 64;   // 1563

  // layer 0: A = xh + xl (split f32)
  k_mgemm<<<GB, 256, 0, stream>>>(xh, nullptr, nullptr, xl, 1, W0h, W0l,
                                  dinv, g, nullptr, 0, 0, nullptr);
  k_aggr<<<NN / 4, 256, 0, stream>>>(rp, sorted, g, dinv, b0, xs0);
  // layer 1
  k_mgemm<<<GB, 256, 0, stream>>>(xs0, nullptr, nullptr, nullptr, 1, W1h, W1l,
                                  dinv, g, nullptr, 0, 0, nullptr);
  k_aggr<<<NN / 4, 256, 0, stream>>>(rp, sorted, g, dinv, b1, xs1);
  // layer 2
  k_mgemm<<<GB, 256, 0, stream>>>(xs1, nullptr, nullptr, nullptr, 1, W2h, W2l,
                                  dinv, g, nullptr, 0, 0, nullptr);
  k_aggr<<<NN / 4, 256, 0, stream>>>(rp, sorted, g, dinv, b2, xs2);
  // projection: z1 = relu(hcat @ Wp0^T + bp0)  (bf16)
  k_mgemm<<<GB, 256, 0, stream>>>(xs0, xs1, xs2, nullptr, 3, Wp0h, Wp0l,
                                  nullptr, nullptr, bp0, 1, 1, z1);
  // out = z1 @ Wp1^T + bp1  (f32)
  k_mgemm<<<GB, 256, 0, stream>>>(z1, nullptr, nullptr, nullptr, 1, Wp1h, Wp1l,
                                  nullptr, nullptr, bp1, 0, 0, out);
}

// Round 7
// 624.697 us; speedup vs baseline: 4.9988x; 1.2277x over previous
//
#include <hip/hip_runtime.h>
#include <hip/hip_bf16.h>

#define NN 100000
#define NE 1600000
#define D  128

typedef unsigned short u16;
typedef unsigned int   u32;
typedef __attribute__((ext_vector_type(8))) short short8v;
typedef __attribute__((ext_vector_type(4))) float f32x4;

__device__ __forceinline__ float b2f(u16 u){
  union { u32 i; float f; } v; v.i = ((u32)u) << 16; return v.f;
}
__device__ __forceinline__ u16 f2b(float f){
  union { float f; u32 i; } v; v.f = f;
  u32 r = v.i + 0x7fffu + ((v.i >> 16) & 1u);   // round-to-nearest-even
  return (u16)(r >> 16);
}

// ---------------- split f32 -> bf16 hi + bf16 lo ----------------
__global__ void k_split(const float* __restrict__ s, u16* __restrict__ hi,
                        u16* __restrict__ lo, int n4){
  int i = blockIdx.x * 256 + threadIdx.x;
  if (i >= n4) return;
  float4 v = ((const float4*)s)[i];
  ushort4 h, l;
  h.x = f2b(v.x); l.x = f2b(v.x - b2f(h.x));
  h.y = f2b(v.y); l.y = f2b(v.y - b2f(h.y));
  h.z = f2b(v.z); l.z = f2b(v.z - b2f(h.z));
  h.w = f2b(v.w); l.w = f2b(v.w - b2f(h.w));
  ((ushort4*)hi)[i] = h; ((ushort4*)lo)[i] = l;
}

// ---------------- CSR build ----------------
__global__ void k_count(const int* __restrict__ dst, int* __restrict__ cnt){
  int e = blockIdx.x * 256 + threadIdx.x;
  if (e < NE) atomicAdd(&cnt[dst[e]], 1);
}

__global__ __launch_bounds__(256) void k_scan1(const int* __restrict__ cnt,
                                               int* __restrict__ rp,
                                               int* __restrict__ partials){
  int i = blockIdx.x * 256 + threadIdx.x;
  int v = (i < NN) ? cnt[i] : 0;
  int lane = threadIdx.x & 63, w = threadIdx.x >> 6;
  int s = v;
  #pragma unroll
  for (int off = 1; off < 64; off <<= 1){
    int t = __shfl_up(s, off, 64);
    if (lane >= off) s += t;
  }
  __shared__ int wsum[4];
  if (lane == 63) wsum[w] = s;
  __syncthreads();
  int add = 0;
  #pragma unroll
  for (int k = 0; k < 4; ++k) if (k < w) add += wsum[k];
  s += add;
  if (i < NN) rp[i] = s - v;
  if (threadIdx.x == 255) partials[blockIdx.x] = s;
}

__global__ __launch_bounds__(512) void k_scan2(int* __restrict__ partials, int nb){
  int i = threadIdx.x;
  int v = (i < nb) ? partials[i] : 0;
  int lane = i & 63, w = i >> 6;
  int s = v;
  #pragma unroll
  for (int off = 1; off < 64; off <<= 1){
    int t = __shfl_up(s, off, 64);
    if (lane >= off) s += t;
  }
  __shared__ int wsum[8];
  if (lane == 63) wsum[w] = s;
  __syncthreads();
  int add = 0;
  #pragma unroll
  for (int k = 0; k < 8; ++k) if (k < w) add += wsum[k];
  s += add;
  if (i < nb) partials[i] = s - v;
}

__global__ void k_scan3(int* __restrict__ rp, const int* __restrict__ partials,
                        const int* __restrict__ cnt,
                        int* __restrict__ cursor, float* __restrict__ dinv){
  int i = blockIdx.x * 256 + threadIdx.x;
  if (i < NN){
    int r = rp[i] + partials[blockIdx.x];
    rp[i] = r;
    cursor[i] = r;
    dinv[i] = rsqrtf(1.0f + (float)cnt[i]);
  }
  if (i == 0) rp[NN] = NE;
}

__global__ void k_fill(const int* __restrict__ src, const int* __restrict__ dst,
                       int* __restrict__ cursor, int* __restrict__ sorted){
  int e = blockIdx.x * 256 + threadIdx.x;
  if (e < NE){
    int pos = atomicAdd(&cursor[dst[e]], 1);
    sorted[pos] = src[e];
  }
}

// ---------------- MFMA GEMM ----------------
// out[n][128] = A @ W^T.  A = up to 3 bf16 chunks [NN][128] (concat on K);
// al0 (optional) = lo-part of chunk 0 (split-f32).  Wh/Wl bf16 [128][kch*128].
// mode A (dinv): g_out[row][col] = bf16(h*dinv[row])
// mode B: out = optional_relu(h + bias) -> bf16 or f32.
__global__ __launch_bounds__(256) void k_mgemm(
    const u16* __restrict__ a0, const u16* __restrict__ a1, const u16* __restrict__ a2,
    const u16* __restrict__ al0, int kch,
    const u16* __restrict__ Wh, const u16* __restrict__ Wl,
    const float* __restrict__ dinv, u16* __restrict__ g_out,
    const float* __restrict__ bias, int relu, int out_bf16,
    void* __restrict__ outp)
{
  __shared__ u16 WHs[16384];   // 32KB, XOR-swizzled rows
  __shared__ u16 WLs[16384];   // 32KB
  const int tid  = threadIdx.x;
  const int w    = tid >> 6, lane = tid & 63;
  const int c    = lane & 15, q = lane >> 4;
  const int rowbase = blockIdx.x * 64 + w * 16;
  const int wstride = kch * D;
  const int swz = (c & 7) << 4;

  int arow = rowbase + c;
  if (arow >= NN) arow = NN - 1;        // clamp; stores are predicated

  f32x4 acc[8];
  #pragma unroll
  for (int f = 0; f < 8; ++f) acc[f] = (f32x4){0.f, 0.f, 0.f, 0.f};

  for (int cc = 0; cc < kch; ++cc){
    if (cc) __syncthreads();
    for (int t = 0; t < 2; ++t){
      const u16* Wsrc = t ? Wl : Wh;
      char* Ldst = (char*)(t ? WLs : WHs);
      for (int idx = tid; idx < 2048; idx += 256){
        int o = idx >> 4, ks = (idx & 15) * 8;
        uint4 v = *(const uint4*)(Wsrc + o * wstride + cc * D + ks);
        *(uint4*)(Ldst + ((o * 256 + ks * 2) ^ ((o & 7) << 4))) = v;
      }
    }
    __syncthreads();

    const u16* ach = (cc == 0) ? a0 : ((cc == 1) ? a1 : a2);
    #pragma unroll
    for (int kk = 0; kk < 4; ++kk){
      const int koff = kk * 32 + q * 8;
      short8v ah = *(const short8v*)(ach + arow * D + koff);
      short8v alv;
      if (al0) alv = *(const short8v*)(al0 + arow * D + koff);
      #pragma unroll
      for (int f = 0; f < 8; ++f){
        const int lrow = f * 16 + c;
        const int lbyte = (lrow * 256 + kk * 64 + q * 16) ^ swz;
        short8v bh = *(const short8v*)((const char*)WHs + lbyte);
        short8v bl = *(const short8v*)((const char*)WLs + lbyte);
        acc[f] = __builtin_amdgcn_mfma_f32_16x16x32_bf16(ah, bh, acc[f], 0, 0, 0);
        acc[f] = __builtin_amdgcn_mfma_f32_16x16x32_bf16(ah, bl, acc[f], 0, 0, 0);
        if (al0)
          acc[f] = __builtin_amdgcn_mfma_f32_16x16x32_bf16(alv, bh, acc[f], 0, 0, 0);
      }
    }
  }

  if (dinv){
    #pragma unroll
    for (int i = 0; i < 4; ++i){
      int row = rowbase + q * 4 + i;
      if (row < NN){
        float di = dinv[row];
        #pragma unroll
        for (int f = 0; f < 8; ++f)
          g_out[row * D + f * 16 + c] = f2b(acc[f][i] * di);
      }
    }
  } else {
    float bv[8];
    #pragma unroll
    for (int f = 0; f < 8; ++f) bv[f] = bias[f * 16 + c];
    #pragma unroll
    for (int i = 0; i < 4; ++i){
      int row = rowbase + q * 4 + i;
      if (row < NN){
        #pragma unroll
        for (int f = 0; f < 8; ++f){
          float o = acc[f][i] + bv[f];
          if (relu) o = fmaxf(o, 0.f);
          if (out_bf16) ((u16*)outp)[row * D + f * 16 + c] = f2b(o);
          else          ((float*)outp)[row * D + f * 16 + c] = o;
        }
      }
    }
  }
}

// ---------------- CSR aggregation (bf16 g), fused epilogue ----------------
// wave per node, lane l holds features {2l, 2l+1} packed in one u32 of g
__global__ __launch_bounds__(256) void k_aggr(
    const int* __restrict__ rp, const int* __restrict__ sorted,
    const u32* __restrict__ g, const float* __restrict__ dinv,
    const float* __restrict__ bias, u16* __restrict__ xs)
{
  int node = blockIdx.x * 4 + (threadIdx.x >> 6);
  int l = threadIdx.x & 63;
  int e0 = rp[node], e1 = rp[node + 1];
  u32 sv = g[node * 64 + l];               // self-loop term
  float ax = b2f((u16)sv), ay = b2f((u16)(sv >> 16));
  int e = e0;
  for (; e + 3 < e1; e += 4){
    int s0 = sorted[e], s1 = sorted[e + 1];
    int s2 = sorted[e + 2], s3 = sorted[e + 3];
    u32 v0 = g[s0 * 64 + l], v1 = g[s1 * 64 + l];
    u32 v2 = g[s2 * 64 + l], v3 = g[s3 * 64 + l];
    ax += b2f((u16)v0) + b2f((u16)v1) + b2f((u16)v2) + b2f((u16)v3);
    ay += b2f((u16)(v0 >> 16)) + b2f((u16)(v1 >> 16))
        + b2f((u16)(v2 >> 16)) + b2f((u16)(v3 >> 16));
  }
  for (; e < e1; ++e){
    u32 v0 = g[sorted[e] * 64 + l];
    ax += b2f((u16)v0); ay += b2f((u16)(v0 >> 16));
  }
  float dn = dinv[node];
  float o0 = fmaxf(fmaf(ax, dn, bias[2 * l]),     0.f);
  float o1 = fmaxf(fmaf(ay, dn, bias[2 * l + 1]), 0.f);
  u32 pk = ((u32)f2b(o1) << 16) | (u32)f2b(o0);
  ((u32*)xs)[node * 64 + l] = pk;
}

extern "C" void kernel_launch(void* const* d_in, const int* in_sizes, int n_in,
                              void* d_out, int out_size, void* d_ws, size_t ws_size,
                              hipStream_t stream)
{
  const float* x   = (const float*)d_in[0];
  const int*   ei  = (const int*)d_in[1];
  const float* W0  = (const float*)d_in[2];
  const float* b0  = (const float*)d_in[3];
  const float* W1  = (const float*)d_in[4];
  const float* b1  = (const float*)d_in[5];
  const float* W2  = (const float*)d_in[6];
  const float* b2  = (const float*)d_in[7];
  const float* Wp0 = (const float*)d_in[8];
  const float* bp0 = (const float*)d_in[9];
  const float* Wp1 = (const float*)d_in[10];
  const float* bp1 = (const float*)d_in[11];
  const int* src = ei;
  const int* dst = ei + NE;

  char* ws = (char*)d_ws;
  float* dinv    = (float*)(ws);                    // 400KB
  int*   cnt     = (int*)  (ws + (512u << 10));
  int*   rp      = (int*)  (ws + (1024u << 10));
  int*   cursor  = (int*)  (ws + (1536u << 10));
  int*   partials= (int*)  (ws + (2048u << 10));
  int*   sorted  = (int*)  (ws + (2560u << 10));    // 6.4MB
  // weight splits at 9MB
  u16* W0h = (u16*)(ws + 9437184u);            u16* W0l = W0h + 16384;
  u16* W1h = W0l + 16384;                      u16* W1l = W1h + 16384;
  u16* W2h = W1l + 16384;                      u16* W2l = W2h + 16384;
  u16* Wp0h = W2l + 16384;                     u16* Wp0l = Wp0h + 49152;
  u16* Wp1h = Wp0l + 49152;                    u16* Wp1l = Wp1h + 16384;
  u16*  g    = (u16*)  (ws + (16384u << 10));       // 25.6MB (bf16)
  u16*  xs0  = (u16*)  (ws + (81920u << 10));       // 25.6MB each
  u16*  xs1  = xs0 + NN * D;
  u16*  xs2  = xs1 + NN * D;
  u16*  z1   = (u16*)(ws + (49152u << 10));         // 25.6MB (separate from g)
  u16*  xh   = xs2;              // x hi/lo alias xs2/xs1 (dead before overwrite)
  u16*  xl   = xs1;
  float* out = (float*)d_out;

  const int NB = (NN + 255) / 256;   // 391

  // input conversions
  k_split<<<12500, 256, 0, stream>>>(x, xh, xl, NN * D / 4);
  k_split<<<16, 256, 0, stream>>>(W0, W0h, W0l, 16384 / 4);
  k_split<<<16, 256, 0, stream>>>(W1, W1h, W1l, 16384 / 4);
  k_split<<<16, 256, 0, stream>>>(W2, W2h, W2l, 16384 / 4);
  k_split<<<48, 256, 0, stream>>>(Wp0, Wp0h, Wp0l, 49152 / 4);
  k_split<<<16, 256, 0, stream>>>(Wp1, Wp1h, Wp1l, 16384 / 4);

  // CSR build
  hipMemsetAsync(cnt, 0, NN * sizeof(int), stream);
  k_count<<<NE / 256, 256, 0, stream>>>(dst, cnt);
  k_scan1<<<NB, 256, 0, stream>>>(cnt, rp, partials);
  k_scan2<<<1, 512, 0, stream>>>(partials, NB);
  k_scan3<<<NB, 256, 0, stream>>>(rp, partials, cnt, cursor, dinv);
  k_fill <<<NE / 256, 256, 0, stream>>>(src, dst, cursor, sorted);

  const int GB = (NN + 63) / 64;   // 1563

  // layer 0: A = xh + xl (split f32)
  k_mgemm<<<GB, 256, 0, stream>>>(xh, nullptr, nullptr, xl, 1, W0h, W0l,
                                  dinv, g, nullptr, 0, 0, nullptr);
  k_aggr<<<NN / 4, 256, 0, stream>>>(rp, sorted, (const u32*)g, dinv, b0, xs0);
  // layer 1
  k_mgemm<<<GB, 256, 0, stream>>>(xs0, nullptr, nullptr, nullptr, 1, W1h, W1l,
                                  dinv, g, nullptr, 0, 0, nullptr);
  k_aggr<<<NN / 4, 256, 0, stream>>>(rp, sorted, (const u32*)g, dinv, b1, xs1);
  // layer 2
  k_mgemm<<<GB, 256, 0, stream>>>(xs1, nullptr, nullptr, nullptr, 1, W2h, W2l,
                                  dinv, g, nullptr, 0, 0, nullptr);
  k_aggr<<<NN / 4, 256, 0, stream>>>(rp, sorted, (const u32*)g, dinv, b2, xs2);
  // projection: z1 = relu(hcat @ Wp0^T + bp0)  (bf16)
  k_mgemm<<<GB, 256, 0, stream>>>(xs0, xs1, xs2, nullptr, 3, Wp0h, Wp0l,
                                  nullptr, nullptr, bp0, 1, 1, z1);
  // out = z1 @ Wp1^T + bp1  (f32)
  k_mgemm<<<GB, 256, 0, stream>>>(z1, nullptr, nullptr, nullptr, 1, Wp1h, Wp1l,
                                  nullptr, nullptr, bp1, 0, 0, out);
}

// Round 8
// 577.351 us; speedup vs baseline: 5.4087x; 1.0820x over previous
//
#include <hip/hip_runtime.h>
#include <hip/hip_bf16.h>

#define NN 100000
#define NE 1600000
#define D  128
#define BPB 12500          // nodes per dst-bucket (8 buckets)
#define EPB 2048           // edges per binning block

typedef unsigned short u16;
typedef unsigned int   u32;
typedef __attribute__((ext_vector_type(8))) short short8v;
typedef __attribute__((ext_vector_type(4))) float f32x4;

__device__ __forceinline__ float b2f(u16 u){
  union { u32 i; float f; } v; v.i = ((u32)u) << 16; return v.f;
}
__device__ __forceinline__ u16 f2b(float f){
  union { float f; u32 i; } v; v.f = f;
  u32 r = v.i + 0x7fffu + ((v.i >> 16) & 1u);   // round-to-nearest-even
  return (u16)(r >> 16);
}

// ---------------- split f32 -> bf16 hi + bf16 lo (weights only) ----------------
__global__ void k_split(const float* __restrict__ s, u16* __restrict__ hi,
                        u16* __restrict__ lo, int n4){
  int i = blockIdx.x * 256 + threadIdx.x;
  if (i >= n4) return;
  float4 v = ((const float4*)s)[i];
  ushort4 h, l;
  h.x = f2b(v.x); l.x = f2b(v.x - b2f(h.x));
  h.y = f2b(v.y); l.y = f2b(v.y - b2f(h.y));
  h.z = f2b(v.z); l.z = f2b(v.z - b2f(h.z));
  h.w = f2b(v.w); l.w = f2b(v.w - b2f(h.w));
  ((ushort4*)hi)[i] = h; ((ushort4*)lo)[i] = l;
}

// ---------------- CSR build ----------------
__global__ void k_count(const int* __restrict__ dst, int* __restrict__ cnt){
  int e = blockIdx.x * 256 + threadIdx.x;
  if (e < NE) atomicAdd(&cnt[dst[e]], 1);
}

__global__ __launch_bounds__(256) void k_scan1(const int* __restrict__ cnt,
                                               int* __restrict__ rp,
                                               int* __restrict__ partials){
  int i = blockIdx.x * 256 + threadIdx.x;
  int v = (i < NN) ? cnt[i] : 0;
  int lane = threadIdx.x & 63, w = threadIdx.x >> 6;
  int s = v;
  #pragma unroll
  for (int off = 1; off < 64; off <<= 1){
    int t = __shfl_up(s, off, 64);
    if (lane >= off) s += t;
  }
  __shared__ int wsum[4];
  if (lane == 63) wsum[w] = s;
  __syncthreads();
  int add = 0;
  #pragma unroll
  for (int k = 0; k < 4; ++k) if (k < w) add += wsum[k];
  s += add;
  if (i < NN) rp[i] = s - v;
  if (threadIdx.x == 255) partials[blockIdx.x] = s;
}

__global__ __launch_bounds__(512) void k_scan2(int* __restrict__ partials, int nb){
  int i = threadIdx.x;
  int v = (i < nb) ? partials[i] : 0;
  int lane = i & 63, w = i >> 6;
  int s = v;
  #pragma unroll
  for (int off = 1; off < 64; off <<= 1){
    int t = __shfl_up(s, off, 64);
    if (lane >= off) s += t;
  }
  __shared__ int wsum[8];
  if (lane == 63) wsum[w] = s;
  __syncthreads();
  int add = 0;
  #pragma unroll
  for (int k = 0; k < 8; ++k) if (k < w) add += wsum[k];
  s += add;
  if (i < nb) partials[i] = s - v;
}

// finalize rp, init cursor + bucket cursors, dinv
__global__ void k_scan3(int* __restrict__ rp, const int* __restrict__ partials,
                        const int* __restrict__ cnt,
                        int* __restrict__ cursor, int* __restrict__ bcur,
                        float* __restrict__ dinv){
  int i = blockIdx.x * 256 + threadIdx.x;
  if (i < NN){
    int r = rp[i] + partials[blockIdx.x];
    rp[i] = r;
    cursor[i] = r;
    if ((i % BPB) == 0) bcur[i / BPB] = r;   // bucket region start in sorted/pairs
    dinv[i] = rsqrtf(1.0f + (float)cnt[i]);
  }
  if (i == 0) rp[NN] = NE;
}

// pass A: LDS-bin edges by dst bucket, write (dst,src) pairs bucket-grouped
__global__ __launch_bounds__(256) void k_fill2a(
    const int* __restrict__ src, const int* __restrict__ dst,
    int* __restrict__ bcur, uint2* __restrict__ pairs)
{
  __shared__ int bcnt[8], boff[8], bbase[8], bsave[8];
  __shared__ uint2 buf[EPB];
  const int tid = threadIdx.x;
  const int e0 = blockIdx.x * EPB + tid * 8;
  if (tid < 8) bcnt[tid] = 0;
  __syncthreads();
  int d[8], s[8], nval = 0;
  if (e0 + 8 <= NE){
    int4 d0 = *(const int4*)(dst + e0), d1 = *(const int4*)(dst + e0 + 4);
    int4 s0 = *(const int4*)(src + e0), s1 = *(const int4*)(src + e0 + 4);
    d[0]=d0.x; d[1]=d0.y; d[2]=d0.z; d[3]=d0.w;
    d[4]=d1.x; d[5]=d1.y; d[6]=d1.z; d[7]=d1.w;
    s[0]=s0.x; s[1]=s0.y; s[2]=s0.z; s[3]=s0.w;
    s[4]=s1.x; s[5]=s1.y; s[6]=s1.z; s[7]=s1.w;
    nval = 8;
  } else {
    for (int j = 0; j < 8; ++j){
      int e = e0 + j;
      if (e < NE){ d[j] = dst[e]; s[j] = src[e]; ++nval; }
    }
  }
  for (int j = 0; j < 8; ++j)
    if (j < nval) atomicAdd(&bcnt[d[j] / BPB], 1);
  __syncthreads();
  if (tid == 0){
    int run = 0;
    #pragma unroll
    for (int b = 0; b < 8; ++b){
      boff[b] = run; bsave[b] = bcnt[b]; run += bcnt[b]; bcnt[b] = 0;
    }
  }
  __syncthreads();
  if (tid < 8) bbase[tid] = atomicAdd(&bcur[tid], bsave[tid]);
  for (int j = 0; j < 8; ++j)
    if (j < nval){
      int b = d[j] / BPB;
      int p = boff[b] + atomicAdd(&bcnt[b], 1);
      buf[p] = make_uint2((u32)d[j], (u32)s[j]);
    }
  __syncthreads();
  int total = boff[7] + bsave[7];
  for (int i = tid; i < total; i += 256){
    int b = 0;
    #pragma unroll
    for (int k = 1; k < 8; ++k) b += (i >= boff[k]);
    pairs[bbase[b] + (i - boff[b])] = buf[i];
  }
}

// pass B: scatter within L2-resident bucket regions
__global__ void k_fill2b(const uint2* __restrict__ pairs,
                         int* __restrict__ cursor, int* __restrict__ sorted){
  int e = blockIdx.x * 256 + threadIdx.x;
  if (e < NE){
    uint2 p = pairs[e];
    int pos = atomicAdd(&cursor[p.x], 1);
    sorted[pos] = p.y;
  }
}

// ---------------- MFMA GEMM ----------------
// out[n][128] = A @ W^T.  A = up to 3 bf16 chunks [NN][128] (concat on K);
// a0f (optional): chunk 0 is f32, split to bf16 hi/lo in-register.
// Wh/Wl bf16 [128][kch*128].
// mode A (dinv): g_out[row][col] = bf16(h*dinv[row])
// mode B: out = optional_relu(h + bias) -> bf16 or f32.
__global__ __launch_bounds__(256) void k_mgemm(
    const u16* __restrict__ a0, const u16* __restrict__ a1, const u16* __restrict__ a2,
    const float* __restrict__ a0f, int kch,
    const u16* __restrict__ Wh, const u16* __restrict__ Wl,
    const float* __restrict__ dinv, u16* __restrict__ g_out,
    const float* __restrict__ bias, int relu, int out_bf16,
    void* __restrict__ outp)
{
  __shared__ u16 WHs[16384];   // 32KB, XOR-swizzled rows
  __shared__ u16 WLs[16384];   // 32KB
  const int tid  = threadIdx.x;
  const int w    = tid >> 6, lane = tid & 63;
  const int c    = lane & 15, q = lane >> 4;
  const int rowbase = blockIdx.x * 64 + w * 16;
  const int wstride = kch * D;
  const int swz = (c & 7) << 4;

  int arow = rowbase + c;
  if (arow >= NN) arow = NN - 1;        // clamp; stores are predicated

  f32x4 acc[8];
  #pragma unroll
  for (int f = 0; f < 8; ++f) acc[f] = (f32x4){0.f, 0.f, 0.f, 0.f};

  for (int cc = 0; cc < kch; ++cc){
    if (cc) __syncthreads();
    for (int t = 0; t < 2; ++t){
      const u16* Wsrc = t ? Wl : Wh;
      char* Ldst = (char*)(t ? WLs : WHs);
      for (int idx = tid; idx < 2048; idx += 256){
        int o = idx >> 4, ks = (idx & 15) * 8;
        uint4 v = *(const uint4*)(Wsrc + o * wstride + cc * D + ks);
        *(uint4*)(Ldst + ((o * 256 + ks * 2) ^ ((o & 7) << 4))) = v;
      }
    }
    __syncthreads();

    const int useF32 = (cc == 0) && (a0f != nullptr);
    const u16* ach = (cc == 0) ? a0 : ((cc == 1) ? a1 : a2);
    #pragma unroll
    for (int kk = 0; kk < 4; ++kk){
      const int koff = kk * 32 + q * 8;
      short8v ah, alv;
      if (useF32){
        float4 v0 = *(const float4*)(a0f + arow * D + koff);
        float4 v1 = *(const float4*)(a0f + arow * D + koff + 4);
        float vv[8] = {v0.x, v0.y, v0.z, v0.w, v1.x, v1.y, v1.z, v1.w};
        #pragma unroll
        for (int j = 0; j < 8; ++j){
          u16 h = f2b(vv[j]);
          ah[j]  = (short)h;
          alv[j] = (short)f2b(vv[j] - b2f(h));
        }
      } else {
        ah = *(const short8v*)(ach + arow * D + koff);
        alv = ah;   // unused
      }
      #pragma unroll
      for (int f = 0; f < 8; ++f){
        const int lrow = f * 16 + c;
        const int lbyte = (lrow * 256 + kk * 64 + q * 16) ^ swz;
        short8v bh = *(const short8v*)((const char*)WHs + lbyte);
        short8v bl = *(const short8v*)((const char*)WLs + lbyte);
        acc[f] = __builtin_amdgcn_mfma_f32_16x16x32_bf16(ah, bh, acc[f], 0, 0, 0);
        acc[f] = __builtin_amdgcn_mfma_f32_16x16x32_bf16(ah, bl, acc[f], 0, 0, 0);
        if (useF32)
          acc[f] = __builtin_amdgcn_mfma_f32_16x16x32_bf16(alv, bh, acc[f], 0, 0, 0);
      }
    }
  }

  if (dinv){
    #pragma unroll
    for (int i = 0; i < 4; ++i){
      int row = rowbase + q * 4 + i;
      if (row < NN){
        float di = dinv[row];
        #pragma unroll
        for (int f = 0; f < 8; ++f)
          g_out[row * D + f * 16 + c] = f2b(acc[f][i] * di);
      }
    }
  } else {
    float bv[8];
    #pragma unroll
    for (int f = 0; f < 8; ++f) bv[f] = bias[f * 16 + c];
    #pragma unroll
    for (int i = 0; i < 4; ++i){
      int row = rowbase + q * 4 + i;
      if (row < NN){
        #pragma unroll
        for (int f = 0; f < 8; ++f){
          float o = acc[f][i] + bv[f];
          if (relu) o = fmaxf(o, 0.f);
          if (out_bf16) ((u16*)outp)[row * D + f * 16 + c] = f2b(o);
          else          ((float*)outp)[row * D + f * 16 + c] = o;
        }
      }
    }
  }
}

// ---------------- CSR aggregation (bf16 g), fused epilogue ----------------
__global__ __launch_bounds__(256) void k_aggr(
    const int* __restrict__ rp, const int* __restrict__ sorted,
    const u32* __restrict__ g, const float* __restrict__ dinv,
    const float* __restrict__ bias, u16* __restrict__ xs)
{
  int node = blockIdx.x * 4 + (threadIdx.x >> 6);
  int l = threadIdx.x & 63;
  int e0 = rp[node], e1 = rp[node + 1];
  u32 sv = g[node * 64 + l];               // self-loop term
  float ax = b2f((u16)sv), ay = b2f((u16)(sv >> 16));
  int e = e0;
  for (; e + 3 < e1; e += 4){
    int s0 = sorted[e], s1 = sorted[e + 1];
    int s2 = sorted[e + 2], s3 = sorted[e + 3];
    u32 v0 = g[s0 * 64 + l], v1 = g[s1 * 64 + l];
    u32 v2 = g[s2 * 64 + l], v3 = g[s3 * 64 + l];
    ax += b2f((u16)v0) + b2f((u16)v1) + b2f((u16)v2) + b2f((u16)v3);
    ay += b2f((u16)(v0 >> 16)) + b2f((u16)(v1 >> 16))
        + b2f((u16)(v2 >> 16)) + b2f((u16)(v3 >> 16));
  }
  for (; e < e1; ++e){
    u32 v0 = g[sorted[e] * 64 + l];
    ax += b2f((u16)v0); ay += b2f((u16)(v0 >> 16));
  }
  float dn = dinv[node];
  float o0 = fmaxf(fmaf(ax, dn, bias[2 * l]),     0.f);
  float o1 = fmaxf(fmaf(ay, dn, bias[2 * l + 1]), 0.f);
  u32 pk = ((u32)f2b(o1) << 16) | (u32)f2b(o0);
  ((u32*)xs)[node * 64 + l] = pk;
}

extern "C" void kernel_launch(void* const* d_in, const int* in_sizes, int n_in,
                              void* d_out, int out_size, void* d_ws, size_t ws_size,
                              hipStream_t stream)
{
  const float* x   = (const float*)d_in[0];
  const int*   ei  = (const int*)d_in[1];
  const float* W0  = (const float*)d_in[2];
  const float* b0  = (const float*)d_in[3];
  const float* W1  = (const float*)d_in[4];
  const float* b1  = (const float*)d_in[5];
  const float* W2  = (const float*)d_in[6];
  const float* b2  = (const float*)d_in[7];
  const float* Wp0 = (const float*)d_in[8];
  const float* bp0 = (const float*)d_in[9];
  const float* Wp1 = (const float*)d_in[10];
  const float* bp1 = (const float*)d_in[11];
  const int* src = ei;
  const int* dst = ei + NE;

  char* ws = (char*)d_ws;
  float* dinv    = (float*)(ws);                    // 400KB
  int*   cnt     = (int*)  (ws + (512u << 10));
  int*   rp      = (int*)  (ws + (1024u << 10));
  int*   cursor  = (int*)  (ws + (1536u << 10));
  int*   partials= (int*)  (ws + (2048u << 10));    // 2KB
  int*   bcur    = (int*)  (ws + (2048u << 10) + 4096); // 32B
  int*   sorted  = (int*)  (ws + (2560u << 10));    // 6.4MB, ends 8.9MB
  u16* W0h = (u16*)(ws + 9437184u);            u16* W0l = W0h + 16384;
  u16* W1h = W0l + 16384;                      u16* W1l = W1h + 16384;
  u16* W2h = W1l + 16384;                      u16* W2l = W2h + 16384;
  u16* Wp0h = W2l + 16384;                     u16* Wp0l = Wp0h + 49152;
  u16* Wp1h = Wp0l + 49152;                    u16* Wp1l = Wp1h + 16384;
  uint2* pairs = (uint2*)(ws + (10240u << 10));     // 12.8MB, ends 22.8MB
  u16*  g    = (u16*)  (ws + (24576u << 10));       // 25.6MB, ends 49.6MB
  u16*  z1   = (u16*)  (ws + (51200u << 10));       // 25.6MB, ends 75.6MB
  u16*  xs0  = (u16*)  (ws + (81920u << 10));       // 25.6MB each
  u16*  xs1  = xs0 + NN * D;
  u16*  xs2  = xs1 + NN * D;
  float* out = (float*)d_out;

  const int NB = (NN + 255) / 256;   // 391

  // weight conversions (tiny)
  k_split<<<16, 256, 0, stream>>>(W0, W0h, W0l, 16384 / 4);
  k_split<<<16, 256, 0, stream>>>(W1, W1h, W1l, 16384 / 4);
  k_split<<<16, 256, 0, stream>>>(W2, W2h, W2l, 16384 / 4);
  k_split<<<48, 256, 0, stream>>>(Wp0, Wp0h, Wp0l, 49152 / 4);
  k_split<<<16, 256, 0, stream>>>(Wp1, Wp1h, Wp1l, 16384 / 4);

  // CSR build
  hipMemsetAsync(cnt, 0, NN * sizeof(int), stream);
  k_count<<<NE / 256, 256, 0, stream>>>(dst, cnt);
  k_scan1<<<NB, 256, 0, stream>>>(cnt, rp, partials);
  k_scan2<<<1, 512, 0, stream>>>(partials, NB);
  k_scan3<<<NB, 256, 0, stream>>>(rp, partials, cnt, cursor, bcur, dinv);
  k_fill2a<<<(NE + EPB - 1) / EPB, 256, 0, stream>>>(src, dst, bcur, pairs);
  k_fill2b<<<NE / 256, 256, 0, stream>>>(pairs, cursor, sorted);

  const int GB = (NN + 63) / 64;   // 1563

  // layer 0: A = x (f32, split in-register)
  k_mgemm<<<GB, 256, 0, stream>>>(nullptr, nullptr, nullptr, x, 1, W0h, W0l,
                                  dinv, g, nullptr, 0, 0, nullptr);
  k_aggr<<<NN / 4, 256, 0, stream>>>(rp, sorted, (const u32*)g, dinv, b0, xs0);
  // layer 1
  k_mgemm<<<GB, 256, 0, stream>>>(xs0, nullptr, nullptr, nullptr, 1, W1h, W1l,
                                  dinv, g, nullptr, 0, 0, nullptr);
  k_aggr<<<NN / 4, 256, 0, stream>>>(rp, sorted, (const u32*)g, dinv, b1, xs1);
  // layer 2
  k_mgemm<<<GB, 256, 0, stream>>>(xs1, nullptr, nullptr, nullptr, 1, W2h, W2l,
                                  dinv, g, nullptr, 0, 0, nullptr);
  k_aggr<<<NN / 4, 256, 0, stream>>>(rp, sorted, (const u32*)g, dinv, b2, xs2);
  // projection: z1 = relu(hcat @ Wp0^T + bp0)  (bf16)
  k_mgemm<<<GB, 256, 0, stream>>>(xs0, xs1, xs2, nullptr, 3, Wp0h, Wp0l,
                                  nullptr, nullptr, bp0, 1, 1, z1);
  // out = z1 @ Wp1^T + bp1  (f32)
  k_mgemm<<<GB, 256, 0, stream>>>(z1, nullptr, nullptr, nullptr, 1, Wp1h, Wp1l,
                                  nullptr, nullptr, bp1, 0, 0, out);
}